// Round 1
// baseline (9171.125 us; speedup 1.0000x reference)
//
#include <hip/hip_runtime.h>
#include <stdint.h>
#include <stddef.h>

#define T_LEN 1024
#define BATCH 64
#define KDIM  256
#define HID   256
#define NGATE 5
#define GROWS (NGATE * HID)   // 1280
#define NGT   (GROWS / 16)    // 80 gate tiles of 16 rows
#define NWG   16              // scan workgroups (H sliced 16 cols each)
#define NWAVE 4
#define NFLAGS (NWG * NWAVE)  // 64 per-wave flags

typedef __attribute__((ext_vector_type(8))) short s16x8;   // 8 bf16 (bit pattern)
typedef __attribute__((ext_vector_type(4))) float f32x4;
typedef __attribute__((ext_vector_type(2))) unsigned int u32x2;

static __device__ __forceinline__ uint16_t f2bf(float f) {
  uint32_t u = __float_as_uint(f);
  uint32_t r = (u + 0x7fffu + ((u >> 16) & 1u)) >> 16;   // RNE
  return (uint16_t)r;
}
static __device__ __forceinline__ float bf2f(uint16_t b) {
  return __uint_as_float(((uint32_t)b) << 16);
}
// load 8 consecutive floats -> bf16x8 fragment
static __device__ __forceinline__ s16x8 cvt8(const float* __restrict__ p) {
  float4 a = *reinterpret_cast<const float4*>(p);
  float4 b = *reinterpret_cast<const float4*>(p + 4);
  union { s16x8 v; uint16_t u[8]; } r;
  r.u[0] = f2bf(a.x); r.u[1] = f2bf(a.y); r.u[2] = f2bf(a.z); r.u[3] = f2bf(a.w);
  r.u[4] = f2bf(b.x); r.u[5] = f2bf(b.y); r.u[6] = f2bf(b.z); r.u[7] = f2bf(b.w);
  return r.v;
}
static __device__ __forceinline__ float sigm(float x)   { return 1.f / (1.f + __expf(-x)); }
static __device__ __forceinline__ float tanh_f(float x) { return 1.f - 2.f / (__expf(2.f * x) + 1.f); }

// ---------------- setup: convert W_ih->bf16, init h buffer / c buffer / flags ----------------
__global__ void setup_kernel(const float* __restrict__ Wih, const float* __restrict__ h0,
                             const float* __restrict__ c0,
                             uint16_t* __restrict__ wihb, uint16_t* __restrict__ hbuf,
                             float* __restrict__ cbuf, uint32_t* __restrict__ flags) {
  int i = blockIdx.x * 256 + threadIdx.x;
  if (i < GROWS * KDIM) wihb[i] = f2bf(Wih[i]);
  if (i < BATCH * HID) {
    hbuf[i] = f2bf(h0[i]);
    hbuf[BATCH * HID + i] = 0;
    cbuf[i] = c0[i];
  }
  if (i < NFLAGS) flags[i] = 0u;
}

// ---------------- x projection: xp[t][b][5H] stored in per-lane MFMA C-fragment layout ----------------
// layout: xp[((lt*4 + bt)*80 + gt)*256 + lane*4 + j]  (bf16)
__global__ __launch_bounds__(256, 2)
void xproj_kernel(const float* __restrict__ x, const uint16_t* __restrict__ wihb,
                  const float* __restrict__ bias, uint16_t* __restrict__ xp, int t0) {
  const int w = threadIdx.x >> 6, lane = threadIdx.x & 63;
  const int r16 = lane & 15, ke = (lane >> 4) * 8;
  const int tA = t0 + (int)blockIdx.x * 2;

  s16x8 A[2][8];
#pragma unroll
  for (int tt = 0; tt < 2; ++tt) {
    const float* ap = x + ((size_t)(tA + tt) * BATCH + w * 16 + r16) * KDIM + ke;
#pragma unroll
    for (int ks = 0; ks < 8; ++ks) A[tt][ks] = cvt8(ap + ks * 32);
  }
  for (int gt = 0; gt < NGT; ++gt) {
    const uint16_t* bp = wihb + (size_t)(gt * 16 + r16) * KDIM + ke;
    s16x8 B[8];
#pragma unroll
    for (int ks = 0; ks < 8; ++ks) B[ks] = *reinterpret_cast<const s16x8*>(bp + ks * 32);
    const float bv = bias[gt * 16 + r16];
#pragma unroll
    for (int tt = 0; tt < 2; ++tt) {
      f32x4 acc = {};
#pragma unroll
      for (int ks = 0; ks < 8; ++ks)
        acc = __builtin_amdgcn_mfma_f32_16x16x32_bf16(A[tt][ks], B[ks], acc, 0, 0, 0);
      const int lt = (int)blockIdx.x * 2 + tt;
      uint32_t w0 = (uint32_t)f2bf(acc[0] + bv) | ((uint32_t)f2bf(acc[1] + bv) << 16);
      uint32_t w1 = (uint32_t)f2bf(acc[2] + bv) | ((uint32_t)f2bf(acc[3] + bv) << 16);
      u32x2 pk = {w0, w1};
      u32x2* dst = (u32x2*)((uint32_t*)(xp + ((size_t)(lt * 4 + w) * NGT + gt) * 256) + lane * 2);
      __builtin_nontemporal_store(pk, dst);
    }
  }
}

// ---------------- sequential scan ----------------
// 16 WGs x 4 waves. WG wg owns H columns [wg*16, wg*16+16). Wave w owns batch tile w (16 rows).
// W_hh fragments resident in VGPRs. c resident in lane registers. One flag barrier per step.
__global__ __launch_bounds__(256, 1)
void scan_kernel(const float* __restrict__ mIn, const float* __restrict__ whh,
                 const uint16_t* __restrict__ xp,
                 uint16_t* __restrict__ hbuf, float* __restrict__ cbuf,
                 uint32_t* flags,
                 float* __restrict__ seq, float* __restrict__ hT, float* __restrict__ cT,
                 int s0, int s1) {
  const int wg = blockIdx.x, w = threadIdx.x >> 6, lane = threadIdx.x & 63;
  const int r16 = lane & 15, ke = (lane >> 4) * 8;
  const int hs = wg * 16 + r16;               // owned H column (B-frag row / C col)
  const int bj0 = w * 16 + (lane >> 4) * 4;   // C/D row base (batch)

  // Resident B fragments: W_hh rows {g*256 + hs}, fp32 -> bf16 once.
  s16x8 Bf[NGATE][8];
#pragma unroll
  for (int g = 0; g < NGATE; ++g) {
    const float* wp = whh + (size_t)(g * HID + hs) * KDIM + ke;
#pragma unroll
    for (int ks = 0; ks < 8; ++ks) Bf[g][ks] = cvt8(wp + ks * 32);
  }
  float c[4];
#pragma unroll
  for (int j = 0; j < 4; ++j) c[j] = cbuf[(size_t)(bj0 + j) * HID + hs];

  for (int s = s0; s < s1; ++s) {
    const int lt = s - s0;
    // prefetch xp + m (independent of h exchange)
    u32x2 xpf[NGATE];
#pragma unroll
    for (int g = 0; g < NGATE; ++g)
      xpf[g] = *reinterpret_cast<const u32x2*>(
          xp + ((size_t)(lt * 4 + w) * NGT + (g * 16 + wg)) * 256 + lane * 4);
    float mv[4];
#pragma unroll
    for (int j = 0; j < 4; ++j) mv[j] = mIn[((size_t)s * BATCH + bj0 + j) * HID + hs];

    if (s > s0) {   // wait for all 64 waves to have published h_s (kernel boundary covers s==s0)
      uint32_t v;
      do {
        v = __hip_atomic_load(&flags[lane], __ATOMIC_RELAXED, __HIP_MEMORY_SCOPE_AGENT);
      } while (!__all((int)(v >= (uint32_t)s)));
      __threadfence();  // acquire: invalidate caches before reading h
    }

    // A fragments: h_s rows (this wave's batch tile) from double buffer
    const uint16_t* hb = hbuf + (size_t)(s & 1) * (BATCH * HID) + (size_t)(w * 16 + r16) * HID + ke;
    s16x8 Af[8];
#pragma unroll
    for (int ks = 0; ks < 8; ++ks) Af[ks] = *reinterpret_cast<const s16x8*>(hb + ks * 32);

    f32x4 acc[NGATE] = {};
#pragma unroll
    for (int ks = 0; ks < 8; ++ks)
#pragma unroll
      for (int g = 0; g < NGATE; ++g)
        acc[g] = __builtin_amdgcn_mfma_f32_16x16x32_bf16(Af[ks], Bf[g][ks], acc[g], 0, 0, 0);

    uint16_t* hw = hbuf + (size_t)((s + 1) & 1) * (BATCH * HID);
    float hnew[4];
#pragma unroll
    for (int j = 0; j < 4; ++j) {
      const float gi = acc[0][j] + bf2f((uint16_t)((j & 1) ? (xpf[0][j >> 1] >> 16) : (xpf[0][j >> 1] & 0xffff)));
      const float gf = acc[1][j] + bf2f((uint16_t)((j & 1) ? (xpf[1][j >> 1] >> 16) : (xpf[1][j >> 1] & 0xffff)));
      const float gg = acc[2][j] + bf2f((uint16_t)((j & 1) ? (xpf[2][j >> 1] >> 16) : (xpf[2][j >> 1] & 0xffff)));
      const float go = acc[3][j] + bf2f((uint16_t)((j & 1) ? (xpf[3][j >> 1] >> 16) : (xpf[3][j >> 1] & 0xffff)));
      const float gr = acc[4][j] + bf2f((uint16_t)((j & 1) ? (xpf[4][j >> 1] >> 16) : (xpf[4][j >> 1] & 0xffff)));
      const float cn = sigm(gf) * c[j] + sigm(gi) * tanh_f(gg) + sigm(gr) * mv[j];
      c[j] = cn;
      const float hn = sigm(go) * tanh_f(cn);
      hnew[j] = hn;
      __builtin_nontemporal_store(hn, seq + ((size_t)s * BATCH + bj0 + j) * HID + hs);
      hw[(size_t)(bj0 + j) * HID + hs] = f2bf(hn);
    }
    if (s < T_LEN - 1) {
      __threadfence();  // release: make h stores device-visible before flag
      if (lane == 0)
        __hip_atomic_store(&flags[wg * NWAVE + w], (uint32_t)(s + 1),
                           __ATOMIC_RELAXED, __HIP_MEMORY_SCOPE_AGENT);
    } else {
#pragma unroll
      for (int j = 0; j < 4; ++j) {
        hT[(size_t)(bj0 + j) * HID + hs] = hnew[j];
        cT[(size_t)(bj0 + j) * HID + hs] = c[j];
      }
    }
  }
  // persist c for next chunk (and harmlessly at the end)
#pragma unroll
  for (int j = 0; j < 4; ++j) cbuf[(size_t)(bj0 + j) * HID + hs] = c[j];
}

extern "C" void kernel_launch(void* const* d_in, const int* in_sizes, int n_in,
                              void* d_out, int out_size, void* d_ws, size_t ws_size,
                              hipStream_t stream) {
  (void)in_sizes; (void)n_in; (void)out_size;
  const float* x    = (const float*)d_in[0];
  const float* mIn  = (const float*)d_in[1];
  const float* h0   = (const float*)d_in[2];
  const float* c0   = (const float*)d_in[3];
  const float* Wih  = (const float*)d_in[4];
  const float* Whh  = (const float*)d_in[5];
  const float* bias = (const float*)d_in[6];
  float* out = (float*)d_out;
  float* seq = out;
  float* hT  = out + (size_t)T_LEN * BATCH * HID;
  float* cT  = hT + (size_t)BATCH * HID;

  // ws tail: wih(bf16) + hbuf(2x, bf16) + cbuf(f32) + flags
  const size_t fixed = (size_t)GROWS * KDIM * 2 + (size_t)2 * BATCH * HID * 2
                     + (size_t)BATCH * HID * 4 + 4096;
  int tchunk = T_LEN;   // shrink chunk until xp chunk + fixed fits ws
  while (tchunk > 2 && (size_t)tchunk * BATCH * GROWS * 2 + fixed > ws_size) tchunk >>= 1;

  char* p = (char*)d_ws;
  uint16_t* xp    = (uint16_t*)p;  p += (size_t)tchunk * BATCH * GROWS * 2;
  uint16_t* wihb  = (uint16_t*)p;  p += (size_t)GROWS * KDIM * 2;
  uint16_t* hbuf  = (uint16_t*)p;  p += (size_t)2 * BATCH * HID * 2;
  float*    cbuf  = (float*)p;     p += (size_t)BATCH * HID * 4;
  uint32_t* flags = (uint32_t*)p;

  setup_kernel<<<dim3((GROWS * KDIM + 255) / 256), dim3(256), 0, stream>>>(
      Wih, h0, c0, wihb, hbuf, cbuf, flags);
  for (int s0 = 0; s0 < T_LEN; s0 += tchunk) {
    xproj_kernel<<<dim3(tchunk / 2), dim3(256), 0, stream>>>(x, wihb, bias, xp, s0);
    scan_kernel<<<dim3(NWG), dim3(256), 0, stream>>>(
        mIn, Whh, xp, hbuf, cbuf, flags, seq, hT, cT, s0, s0 + tchunk);
  }
}

// Round 2
// 5460.208 us; speedup vs baseline: 1.6796x; 1.6796x over previous
//
#include <hip/hip_runtime.h>
#include <stdint.h>
#include <stddef.h>

#define T_LEN 1024
#define BATCH 64
#define KDIM  256
#define HID   256
#define NGATE 5
#define GROWS (NGATE * HID)   // 1280
#define NGT   (GROWS / 16)    // 80 gate tiles of 16 rows
#define NWG   16              // scan workgroups (H sliced 16 cols each)
#define NWAVE 4
#define NFLAGS (NWG * NWAVE)  // 64 per-wave flags

typedef __attribute__((ext_vector_type(8))) short s16x8;   // 8 bf16 (bit pattern)
typedef __attribute__((ext_vector_type(4))) float f32x4;
typedef __attribute__((ext_vector_type(2))) unsigned int u32x2;

static __device__ __forceinline__ uint16_t f2bf(float f) {
  uint32_t u = __float_as_uint(f);
  uint32_t r = (u + 0x7fffu + ((u >> 16) & 1u)) >> 16;   // RNE
  return (uint16_t)r;
}
static __device__ __forceinline__ float bf2f(uint16_t b) {
  return __uint_as_float(((uint32_t)b) << 16);
}
static __device__ __forceinline__ s16x8 cvt8(const float* __restrict__ p) {
  float4 a = *reinterpret_cast<const float4*>(p);
  float4 b = *reinterpret_cast<const float4*>(p + 4);
  union { s16x8 v; uint16_t u[8]; } r;
  r.u[0] = f2bf(a.x); r.u[1] = f2bf(a.y); r.u[2] = f2bf(a.z); r.u[3] = f2bf(a.w);
  r.u[4] = f2bf(b.x); r.u[5] = f2bf(b.y); r.u[6] = f2bf(b.z); r.u[7] = f2bf(b.w);
  return r.v;
}
static __device__ __forceinline__ float sigm(float x)   { return 1.f / (1.f + __expf(-x)); }
static __device__ __forceinline__ float tanh_f(float x) { return 1.f - 2.f / (__expf(2.f * x) + 1.f); }

// Coherent (cross-XCD) h exchange: sc0 sc1 write-through stores / cache-bypass loads.
// No L2 writeback/invalidate fences anywhere in the scan loop.
#define STOREH(base, off, val) \
  asm volatile("global_store_short %0, %1, off offset:" #off " sc0 sc1" \
               :: "v"(base), "v"(val) : "memory")
#define LOADH(dst, base, off) \
  asm volatile("global_load_dwordx4 %0, %1, off offset:" #off " sc0 sc1" \
               : "=v"(dst) : "v"(base) : "memory")

// ---------------- setup ----------------
__global__ void setup_kernel(const float* __restrict__ Wih, const float* __restrict__ h0,
                             const float* __restrict__ c0,
                             uint16_t* __restrict__ wihb, uint16_t* __restrict__ hbuf,
                             float* __restrict__ cbuf, uint32_t* __restrict__ flags) {
  int i = blockIdx.x * 256 + threadIdx.x;
  if (i < GROWS * KDIM) wihb[i] = f2bf(Wih[i]);
  if (i < BATCH * HID) {
    hbuf[i] = f2bf(h0[i]);
    hbuf[BATCH * HID + i] = 0;
    cbuf[i] = c0[i];
  }
  if (i < NFLAGS) flags[i] = 0u;
}

// ---------------- x projection (unchanged) ----------------
__global__ __launch_bounds__(256, 2)
void xproj_kernel(const float* __restrict__ x, const uint16_t* __restrict__ wihb,
                  const float* __restrict__ bias, uint16_t* __restrict__ xp, int t0) {
  const int w = threadIdx.x >> 6, lane = threadIdx.x & 63;
  const int r16 = lane & 15, ke = (lane >> 4) * 8;
  const int tA = t0 + (int)blockIdx.x * 2;

  s16x8 A[2][8];
#pragma unroll
  for (int tt = 0; tt < 2; ++tt) {
    const float* ap = x + ((size_t)(tA + tt) * BATCH + w * 16 + r16) * KDIM + ke;
#pragma unroll
    for (int ks = 0; ks < 8; ++ks) A[tt][ks] = cvt8(ap + ks * 32);
  }
  for (int gt = 0; gt < NGT; ++gt) {
    const uint16_t* bp = wihb + (size_t)(gt * 16 + r16) * KDIM + ke;
    s16x8 B[8];
#pragma unroll
    for (int ks = 0; ks < 8; ++ks) B[ks] = *reinterpret_cast<const s16x8*>(bp + ks * 32);
    const float bv = bias[gt * 16 + r16];
#pragma unroll
    for (int tt = 0; tt < 2; ++tt) {
      f32x4 acc = {};
#pragma unroll
      for (int ks = 0; ks < 8; ++ks)
        acc = __builtin_amdgcn_mfma_f32_16x16x32_bf16(A[tt][ks], B[ks], acc, 0, 0, 0);
      const int lt = (int)blockIdx.x * 2 + tt;
      uint32_t w0 = (uint32_t)f2bf(acc[0] + bv) | ((uint32_t)f2bf(acc[1] + bv) << 16);
      uint32_t w1 = (uint32_t)f2bf(acc[2] + bv) | ((uint32_t)f2bf(acc[3] + bv) << 16);
      u32x2 pk = {w0, w1};
      u32x2* dst = (u32x2*)((uint32_t*)(xp + ((size_t)(lt * 4 + w) * NGT + gt) * 256) + lane * 2);
      __builtin_nontemporal_store(pk, dst);
    }
  }
}

// ---------------- sequential scan ----------------
// 16 WGs x 4 waves; WG owns 16 H cols, wave owns 16 batch rows. W_hh resident in VGPRs,
// c resident in lane regs. Per step: coherent h publish (sc0sc1) + per-wave flag; pollers
// use relaxed agent atomics; h consumed via sc0sc1 loads. No cache-wide fences.
__global__ __launch_bounds__(256, 1)
void scan_kernel(const float* __restrict__ mIn, const float* __restrict__ whh,
                 const uint16_t* __restrict__ xp,
                 uint16_t* __restrict__ hbuf, float* __restrict__ cbuf,
                 uint32_t* flags,
                 float* __restrict__ seq, float* __restrict__ hT, float* __restrict__ cT,
                 int s0, int s1) {
  const int wg = blockIdx.x, w = threadIdx.x >> 6, lane = threadIdx.x & 63;
  const int r16 = lane & 15, ke = (lane >> 4) * 8;
  const int hs = wg * 16 + r16;               // owned H column
  const int bj0 = w * 16 + (lane >> 4) * 4;   // C/D row base (batch)

  s16x8 Bf[NGATE][8];
#pragma unroll
  for (int g = 0; g < NGATE; ++g) {
    const float* wp = whh + (size_t)(g * HID + hs) * KDIM + ke;
#pragma unroll
    for (int ks = 0; ks < 8; ++ks) Bf[g][ks] = cvt8(wp + ks * 32);
  }
  float c[4];
#pragma unroll
  for (int j = 0; j < 4; ++j) c[j] = cbuf[(size_t)(bj0 + j) * HID + hs];

  for (int s = s0; s < s1; ++s) {
    const int lt = s - s0;
    // prefetch xp + m (independent of the h exchange; issued before the wait)
    u32x2 xpf[NGATE];
#pragma unroll
    for (int g = 0; g < NGATE; ++g)
      xpf[g] = *reinterpret_cast<const u32x2*>(
          xp + ((size_t)(lt * 4 + w) * NGT + (g * 16 + wg)) * 256 + lane * 4);
    float mv[4];
#pragma unroll
    for (int j = 0; j < 4; ++j) mv[j] = mIn[((size_t)s * BATCH + bj0 + j) * HID + hs];

    if (s > s0) {   // wait for all 64 waves to have published h_s
      uint32_t v;
      do {
        v = __hip_atomic_load(&flags[lane], __ATOMIC_RELAXED, __HIP_MEMORY_SCOPE_AGENT);
      } while (!__all((int)(v >= (uint32_t)s)));
    }

    // A fragments: h_s (this wave's batch tile) — coherent loads bypassing L1/L2
    const uint16_t* hb = hbuf + (size_t)(s & 1) * (BATCH * HID)
                       + (size_t)(w * 16 + r16) * HID + ke;
    s16x8 Af[8];
    LOADH(Af[0], hb, 0);   LOADH(Af[1], hb, 64);  LOADH(Af[2], hb, 128);
    LOADH(Af[3], hb, 192); LOADH(Af[4], hb, 256); LOADH(Af[5], hb, 320);
    LOADH(Af[6], hb, 384); LOADH(Af[7], hb, 448);
    asm volatile("s_waitcnt vmcnt(0)" ::: "memory");
    __builtin_amdgcn_sched_barrier(0);   // keep MFMAs below the waitcnt (rule #18)

    f32x4 acc[NGATE] = {};
#pragma unroll
    for (int ks = 0; ks < 8; ++ks)
#pragma unroll
      for (int g = 0; g < NGATE; ++g)
        acc[g] = __builtin_amdgcn_mfma_f32_16x16x32_bf16(Af[ks], Bf[g][ks], acc[g], 0, 0, 0);

    float hnew[4];
#pragma unroll
    for (int j = 0; j < 4; ++j) {
      const float gi = acc[0][j] + bf2f((uint16_t)((j & 1) ? (xpf[0][j >> 1] >> 16) : (xpf[0][j >> 1] & 0xffff)));
      const float gf = acc[1][j] + bf2f((uint16_t)((j & 1) ? (xpf[1][j >> 1] >> 16) : (xpf[1][j >> 1] & 0xffff)));
      const float gg = acc[2][j] + bf2f((uint16_t)((j & 1) ? (xpf[2][j >> 1] >> 16) : (xpf[2][j >> 1] & 0xffff)));
      const float go = acc[3][j] + bf2f((uint16_t)((j & 1) ? (xpf[3][j >> 1] >> 16) : (xpf[3][j >> 1] & 0xffff)));
      const float gr = acc[4][j] + bf2f((uint16_t)((j & 1) ? (xpf[4][j >> 1] >> 16) : (xpf[4][j >> 1] & 0xffff)));
      const float cn = sigm(gf) * c[j] + sigm(gi) * tanh_f(gg) + sigm(gr) * mv[j];
      c[j] = cn;
      hnew[j] = sigm(go) * tanh_f(cn);
    }

    // publish h_{s+1}: coherent write-through stores, then flag (critical path)
    uint16_t* hw = hbuf + (size_t)((s + 1) & 1) * (BATCH * HID) + (size_t)bj0 * HID + hs;
    STOREH(hw, 0,    (uint32_t)f2bf(hnew[0]));
    STOREH(hw, 512,  (uint32_t)f2bf(hnew[1]));
    STOREH(hw, 1024, (uint32_t)f2bf(hnew[2]));
    STOREH(hw, 1536, (uint32_t)f2bf(hnew[3]));
    asm volatile("s_waitcnt vmcnt(0)" ::: "memory");
    if (s < T_LEN - 1) {
      if (lane == 0)
        __hip_atomic_store(&flags[wg * NWAVE + w], (uint32_t)(s + 1),
                           __ATOMIC_RELAXED, __HIP_MEMORY_SCOPE_AGENT);
    }

    // off-critical-path outputs (after the publish)
#pragma unroll
    for (int j = 0; j < 4; ++j)
      __builtin_nontemporal_store(hnew[j], seq + ((size_t)s * BATCH + bj0 + j) * HID + hs);
    if (s == T_LEN - 1) {
#pragma unroll
      for (int j = 0; j < 4; ++j) {
        hT[(size_t)(bj0 + j) * HID + hs] = hnew[j];
        cT[(size_t)(bj0 + j) * HID + hs] = c[j];
      }
    }
  }
#pragma unroll
  for (int j = 0; j < 4; ++j) cbuf[(size_t)(bj0 + j) * HID + hs] = c[j];
}

extern "C" void kernel_launch(void* const* d_in, const int* in_sizes, int n_in,
                              void* d_out, int out_size, void* d_ws, size_t ws_size,
                              hipStream_t stream) {
  (void)in_sizes; (void)n_in; (void)out_size;
  const float* x    = (const float*)d_in[0];
  const float* mIn  = (const float*)d_in[1];
  const float* h0   = (const float*)d_in[2];
  const float* c0   = (const float*)d_in[3];
  const float* Wih  = (const float*)d_in[4];
  const float* Whh  = (const float*)d_in[5];
  const float* bias = (const float*)d_in[6];
  float* out = (float*)d_out;
  float* seq = out;
  float* hT  = out + (size_t)T_LEN * BATCH * HID;
  float* cT  = hT + (size_t)BATCH * HID;

  const size_t fixed = (size_t)GROWS * KDIM * 2 + (size_t)2 * BATCH * HID * 2
                     + (size_t)BATCH * HID * 4 + 4096;
  int tchunk = T_LEN;
  while (tchunk > 2 && (size_t)tchunk * BATCH * GROWS * 2 + fixed > ws_size) tchunk >>= 1;

  char* p = (char*)d_ws;
  uint16_t* xp    = (uint16_t*)p;  p += (size_t)tchunk * BATCH * GROWS * 2;
  uint16_t* wihb  = (uint16_t*)p;  p += (size_t)GROWS * KDIM * 2;
  uint16_t* hbuf  = (uint16_t*)p;  p += (size_t)2 * BATCH * HID * 2;
  float*    cbuf  = (float*)p;     p += (size_t)BATCH * HID * 4;
  uint32_t* flags = (uint32_t*)p;

  setup_kernel<<<dim3((GROWS * KDIM + 255) / 256), dim3(256), 0, stream>>>(
      Wih, h0, c0, wihb, hbuf, cbuf, flags);
  for (int s0 = 0; s0 < T_LEN; s0 += tchunk) {
    xproj_kernel<<<dim3(tchunk / 2), dim3(256), 0, stream>>>(x, wihb, bias, xp, s0);
    scan_kernel<<<dim3(NWG), dim3(256), 0, stream>>>(
        mIn, Whh, xp, hbuf, cbuf, flags, seq, hT, cT, s0, s0 + tchunk);
  }
}

// Round 4
// 4696.146 us; speedup vs baseline: 1.9529x; 1.1627x over previous
//
#include <hip/hip_runtime.h>
#include <stdint.h>
#include <stddef.h>

#define T_LEN 1024
#define BATCH 64
#define KDIM  256
#define HID   256
#define NGATE 5
#define GROWS (NGATE * HID)   // 1280
#define NGT   (GROWS / 16)    // 80 gate tiles of 16 rows
#define NWG   16              // scan workgroups (H sliced 16 cols each)

typedef __attribute__((ext_vector_type(8))) short s16x8;   // 8 bf16 (bit pattern)
typedef __attribute__((ext_vector_type(4))) float f32x4;
typedef __attribute__((ext_vector_type(2))) unsigned int u32x2;
typedef __attribute__((ext_vector_type(4))) unsigned int u32x4;

static __device__ __forceinline__ uint16_t f2bf(float f) {
  uint32_t u = __float_as_uint(f);
  uint32_t r = (u + 0x7fffu + ((u >> 16) & 1u)) >> 16;   // RNE
  return (uint16_t)r;
}
static __device__ __forceinline__ float bf2f(uint16_t b) {
  return __uint_as_float(((uint32_t)b) << 16);
}
static __device__ __forceinline__ s16x8 cvt8(const float* __restrict__ p) {
  float4 a = *reinterpret_cast<const float4*>(p);
  float4 b = *reinterpret_cast<const float4*>(p + 4);
  union { s16x8 v; uint16_t u[8]; } r;
  r.u[0] = f2bf(a.x); r.u[1] = f2bf(a.y); r.u[2] = f2bf(a.z); r.u[3] = f2bf(a.w);
  r.u[4] = f2bf(b.x); r.u[5] = f2bf(b.y); r.u[6] = f2bf(b.z); r.u[7] = f2bf(b.w);
  return r.v;
}
static __device__ __forceinline__ float sigm(float x)   { return 1.f / (1.f + __expf(-x)); }
static __device__ __forceinline__ float tanh_f(float x) { return 1.f - 2.f / (__expf(2.f * x) + 1.f); }

// Device-scope tagged h exchange. Each h element is one dword: (bf16 << 16) | step_tag.
// Stores are fire-and-forget; consumers poll the data until all tags match the step.
#define STORET(base, off, val) \
  asm volatile("global_store_dword %0, %1, off offset:" #off " sc0 sc1" \
               :: "v"(base), "v"(val) : "memory")
#define LOADT(dst, base, off) \
  asm volatile("global_load_dwordx4 %0, %1, off offset:" #off " sc0 sc1" \
               : "=v"(dst) : "v"(base) : "memory")
#define CHK(r) bad |= ((r[0] ^ tagv) & 0xffffu) | ((r[1] ^ tagv) & 0xffffu) \
                    | ((r[2] ^ tagv) & 0xffffu) | ((r[3] ^ tagv) & 0xffffu)

// ---------------- setup: W_ih->bf16, tagged h0 into parity0, invalidate parity1 ----------------
__global__ void setup_kernel(const float* __restrict__ Wih, const float* __restrict__ h0,
                             const float* __restrict__ c0,
                             uint16_t* __restrict__ wihb, uint32_t* __restrict__ hbuf32,
                             float* __restrict__ cbuf) {
  int i = blockIdx.x * 256 + threadIdx.x;
  if (i < GROWS * KDIM) wihb[i] = f2bf(Wih[i]);
  if (i < BATCH * HID) {
    hbuf32[i] = ((uint32_t)f2bf(h0[i])) << 16;          // tag 0 (read untagged at s=0)
    hbuf32[BATCH * HID + i] = 0x0000FFFFu;              // invalid tag
    cbuf[i] = c0[i];
  }
}

// ---------------- x projection (unchanged) ----------------
__global__ __launch_bounds__(256, 2)
void xproj_kernel(const float* __restrict__ x, const uint16_t* __restrict__ wihb,
                  const float* __restrict__ bias, uint16_t* __restrict__ xp, int t0) {
  const int w = threadIdx.x >> 6, lane = threadIdx.x & 63;
  const int r16 = lane & 15, ke = (lane >> 4) * 8;
  const int tA = t0 + (int)blockIdx.x * 2;

  s16x8 A[2][8];
#pragma unroll
  for (int tt = 0; tt < 2; ++tt) {
    const float* ap = x + ((size_t)(tA + tt) * BATCH + w * 16 + r16) * KDIM + ke;
#pragma unroll
    for (int ks = 0; ks < 8; ++ks) A[tt][ks] = cvt8(ap + ks * 32);
  }
  for (int gt = 0; gt < NGT; ++gt) {
    const uint16_t* bp = wihb + (size_t)(gt * 16 + r16) * KDIM + ke;
    s16x8 B[8];
#pragma unroll
    for (int ks = 0; ks < 8; ++ks) B[ks] = *reinterpret_cast<const s16x8*>(bp + ks * 32);
    const float bv = bias[gt * 16 + r16];
#pragma unroll
    for (int tt = 0; tt < 2; ++tt) {
      f32x4 acc = {};
#pragma unroll
      for (int ks = 0; ks < 8; ++ks)
        acc = __builtin_amdgcn_mfma_f32_16x16x32_bf16(A[tt][ks], B[ks], acc, 0, 0, 0);
      const int lt = (int)blockIdx.x * 2 + tt;
      uint32_t w0 = (uint32_t)f2bf(acc[0] + bv) | ((uint32_t)f2bf(acc[1] + bv) << 16);
      uint32_t w1 = (uint32_t)f2bf(acc[2] + bv) | ((uint32_t)f2bf(acc[3] + bv) << 16);
      u32x2 pk = {w0, w1};
      u32x2* dst = (u32x2*)((uint32_t*)(xp + ((size_t)(lt * 4 + w) * NGT + gt) * 256) + lane * 2);
      __builtin_nontemporal_store(pk, dst);
    }
  }
}

// ---------------- sequential scan, tagged-data exchange ----------------
// 16 WGs x 4 waves. WG owns 16 H cols; wave owns 16 batch rows -> 4 independent 16-wave
// rings. h_{s} lives in hbuf32 parity (s&1), one tagged dword per element. No flags,
// no acks: publish = 4 fire-and-forget dword stores; consume = poll own data until
// all 64 tags == s. Bounded 1-step ring drift is covered by the parity double-buffer.
__global__ __launch_bounds__(256, 1)
void scan_kernel(const float* __restrict__ mIn, const float* __restrict__ whh,
                 const uint16_t* __restrict__ xp,
                 uint32_t* __restrict__ hbuf32, float* __restrict__ cbuf,
                 float* __restrict__ seq, float* __restrict__ hT, float* __restrict__ cT,
                 int s0, int s1) {
  const int wg = blockIdx.x, w = threadIdx.x >> 6, lane = threadIdx.x & 63;
  const int r16 = lane & 15, ke = (lane >> 4) * 8;
  const int hs = wg * 16 + r16;               // owned H column
  const int row = w * 16 + r16;               // A-fragment batch row
  const int bj0 = w * 16 + (lane >> 4) * 4;   // C/D row base (batch)

  s16x8 Bf[NGATE][8];
#pragma unroll
  for (int g = 0; g < NGATE; ++g) {
    const float* wp = whh + (size_t)(g * HID + hs) * KDIM + ke;
#pragma unroll
    for (int ks = 0; ks < 8; ++ks) Bf[g][ks] = cvt8(wp + ks * 32);
  }
  float c[4];
#pragma unroll
  for (int j = 0; j < 4; ++j) c[j] = cbuf[(size_t)(bj0 + j) * HID + hs];

  for (int s = s0; s < s1; ++s) {
    const int lt = s - s0;
    // prefetch xp + m for this step (overlaps producer store flight / poll drain)
    u32x2 xpf[NGATE];
#pragma unroll
    for (int g = 0; g < NGATE; ++g)
      xpf[g] = *reinterpret_cast<const u32x2*>(
          xp + ((size_t)(lt * 4 + w) * NGT + (g * 16 + wg)) * 256 + lane * 4);
    float mv[4];
#pragma unroll
    for (int j = 0; j < 4; ++j) mv[j] = mIn[((size_t)s * BATCH + bj0 + j) * HID + hs];

    // poll this wave's A-row data until every tag == s (skip check at chunk start)
    const uint32_t* hb32 = hbuf32 + (size_t)(s & 1) * (BATCH * HID) + (size_t)row * HID + ke;
    const uint32_t tagv = (uint32_t)s;
    u32x4 r0, r1, r2, r3, r4, r5, r6, r7, r8, r9, rA, rB, rC, rD, rE, rF;
    for (;;) {
      LOADT(r0, hb32, 0);   LOADT(r1, hb32, 16);  LOADT(r2, hb32, 128); LOADT(r3, hb32, 144);
      LOADT(r4, hb32, 256); LOADT(r5, hb32, 272); LOADT(r6, hb32, 384); LOADT(r7, hb32, 400);
      LOADT(r8, hb32, 512); LOADT(r9, hb32, 528); LOADT(rA, hb32, 640); LOADT(rB, hb32, 656);
      LOADT(rC, hb32, 768); LOADT(rD, hb32, 784); LOADT(rE, hb32, 896); LOADT(rF, hb32, 912);
      asm volatile("s_waitcnt vmcnt(0)" ::: "memory");
      __builtin_amdgcn_sched_barrier(0);
      if (s == s0) break;                       // kernel boundary already synced h_{s0}
      uint32_t bad = 0;
      CHK(r0); CHK(r1); CHK(r2); CHK(r3); CHK(r4); CHK(r5); CHK(r6); CHK(r7);
      CHK(r8); CHK(r9); CHK(rA); CHK(rB); CHK(rC); CHK(rD); CHK(rE); CHK(rF);
      if (__all(bad == 0)) break;
    }
    // unpack tagged dwords -> bf16 A fragments
    s16x8 Af[8];
    union { u32x4 u; s16x8 v; } cv;
#define UNPK(dst, A, B) \
    cv.u[0] = (A[0] >> 16) | (A[1] & 0xffff0000u); \
    cv.u[1] = (A[2] >> 16) | (A[3] & 0xffff0000u); \
    cv.u[2] = (B[0] >> 16) | (B[1] & 0xffff0000u); \
    cv.u[3] = (B[2] >> 16) | (B[3] & 0xffff0000u); \
    dst = cv.v;
    UNPK(Af[0], r0, r1) UNPK(Af[1], r2, r3) UNPK(Af[2], r4, r5) UNPK(Af[3], r6, r7)
    UNPK(Af[4], r8, r9) UNPK(Af[5], rA, rB) UNPK(Af[6], rC, rD) UNPK(Af[7], rE, rF)
#undef UNPK

    f32x4 acc[NGATE] = {};
#pragma unroll
    for (int ks = 0; ks < 8; ++ks)
#pragma unroll
      for (int g = 0; g < NGATE; ++g)
        acc[g] = __builtin_amdgcn_mfma_f32_16x16x32_bf16(Af[ks], Bf[g][ks], acc[g], 0, 0, 0);

    float hnew[4];
#pragma unroll
    for (int j = 0; j < 4; ++j) {
      const float gi = acc[0][j] + bf2f((uint16_t)((j & 1) ? (xpf[0][j >> 1] >> 16) : (xpf[0][j >> 1] & 0xffff)));
      const float gf = acc[1][j] + bf2f((uint16_t)((j & 1) ? (xpf[1][j >> 1] >> 16) : (xpf[1][j >> 1] & 0xffff)));
      const float gg = acc[2][j] + bf2f((uint16_t)((j & 1) ? (xpf[2][j >> 1] >> 16) : (xpf[2][j >> 1] & 0xffff)));
      const float go = acc[3][j] + bf2f((uint16_t)((j & 1) ? (xpf[3][j >> 1] >> 16) : (xpf[3][j >> 1] & 0xffff)));
      const float gr = acc[4][j] + bf2f((uint16_t)((j & 1) ? (xpf[4][j >> 1] >> 16) : (xpf[4][j >> 1] & 0xffff)));
      const float cn = sigm(gf) * c[j] + sigm(gi) * tanh_f(gg) + sigm(gr) * mv[j];
      c[j] = cn;
      hnew[j] = sigm(go) * tanh_f(cn);
    }

    // publish h_{s+1}: tagged dwords, fire-and-forget (consumer validates tags)
    if (s < T_LEN - 1) {
      uint32_t* hw32 = hbuf32 + (size_t)((s + 1) & 1) * (BATCH * HID)
                     + (size_t)bj0 * HID + hs;
      const uint32_t tg = (uint32_t)(s + 1);
      STORET(hw32, 0,    (((uint32_t)f2bf(hnew[0])) << 16) | tg);
      STORET(hw32, 1024, (((uint32_t)f2bf(hnew[1])) << 16) | tg);
      STORET(hw32, 2048, (((uint32_t)f2bf(hnew[2])) << 16) | tg);
      STORET(hw32, 3072, (((uint32_t)f2bf(hnew[3])) << 16) | tg);
    }

    // off-critical-path outputs (plain stores: fast L2 write-back ack)
#pragma unroll
    for (int j = 0; j < 4; ++j)
      seq[((size_t)s * BATCH + bj0 + j) * HID + hs] = hnew[j];
    if (s == T_LEN - 1) {
#pragma unroll
      for (int j = 0; j < 4; ++j) {
        hT[(size_t)(bj0 + j) * HID + hs] = hnew[j];
        cT[(size_t)(bj0 + j) * HID + hs] = c[j];
      }
    }
  }
#pragma unroll
  for (int j = 0; j < 4; ++j) cbuf[(size_t)(bj0 + j) * HID + hs] = c[j];
}

extern "C" void kernel_launch(void* const* d_in, const int* in_sizes, int n_in,
                              void* d_out, int out_size, void* d_ws, size_t ws_size,
                              hipStream_t stream) {
  (void)in_sizes; (void)n_in; (void)out_size;
  const float* x    = (const float*)d_in[0];
  const float* mIn  = (const float*)d_in[1];
  const float* h0   = (const float*)d_in[2];
  const float* c0   = (const float*)d_in[3];
  const float* Wih  = (const float*)d_in[4];
  const float* Whh  = (const float*)d_in[5];
  const float* bias = (const float*)d_in[6];
  float* out = (float*)d_out;
  float* seq = out;
  float* hT  = out + (size_t)T_LEN * BATCH * HID;
  float* cT  = hT + (size_t)BATCH * HID;

  // ws tail: wih(bf16) + hbuf32(2x tagged dwords) + cbuf(f32)
  const size_t fixed = (size_t)GROWS * KDIM * 2 + (size_t)2 * BATCH * HID * 4
                     + (size_t)BATCH * HID * 4 + 4096;
  int tchunk = T_LEN;
  while (tchunk > 2 && (size_t)tchunk * BATCH * GROWS * 2 + fixed > ws_size) tchunk >>= 1;

  char* p = (char*)d_ws;
  uint16_t* xp     = (uint16_t*)p;  p += (size_t)tchunk * BATCH * GROWS * 2;
  uint16_t* wihb   = (uint16_t*)p;  p += (size_t)GROWS * KDIM * 2;
  uint32_t* hbuf32 = (uint32_t*)p;  p += (size_t)2 * BATCH * HID * 4;
  float*    cbuf   = (float*)p;

  setup_kernel<<<dim3((GROWS * KDIM + 255) / 256), dim3(256), 0, stream>>>(
      Wih, h0, c0, wihb, hbuf32, cbuf);
  for (int s0 = 0; s0 < T_LEN; s0 += tchunk) {
    xproj_kernel<<<dim3(tchunk / 2), dim3(256), 0, stream>>>(x, wihb, bias, xp, s0);
    scan_kernel<<<dim3(NWG), dim3(256), 0, stream>>>(
        mIn, Whh, xp, hbuf32, cbuf, seq, hT, cT, s0, s0 + tchunk);
  }
}